// Round 8
// baseline (294.789 us; speedup 1.0000x reference)
//
#include <hip/hip_runtime.h>
#include <hip/hip_bf16.h>
#include <math.h>

#define DIM 64

typedef __attribute__((ext_vector_type(8))) short bf16x8;
typedef __attribute__((ext_vector_type(4))) float f32x4;
typedef unsigned short ushort_t;

__device__ __forceinline__ float silu_f(float x) {
    float e = __expf(-x);
    return x * __builtin_amdgcn_rcpf(1.0f + e);
}
// fast fp32->bf16 RNE (finite inputs)
__device__ __forceinline__ unsigned short f2bf_fast(float x) {
    unsigned u = __builtin_bit_cast(unsigned, x);
    u += 0x7FFFu + ((u >> 16) & 1u);
    return (unsigned short)(u >> 16);
}
// wave-internal LDS sync: lgkmcnt(0) only — no s_barrier, no vmcnt drain
__device__ __forceinline__ void wave_sync() {
    __builtin_amdgcn_wave_barrier();
    __builtin_amdgcn_s_waitcnt(0xC07F);
    __builtin_amdgcn_wave_barrier();
}

// 16-element bf16 dot (two bf16x8 per side)
#if __has_builtin(__builtin_amdgcn_fdot2_f32_bf16)
typedef __attribute__((ext_vector_type(2))) __bf16 bf16x2_t;
__device__ __forceinline__ float dot16_bf16(bf16x8 a0, bf16x8 a1, bf16x8 b0, bf16x8 b1) {
    int4 ua0 = __builtin_bit_cast(int4, a0), ua1 = __builtin_bit_cast(int4, a1);
    int4 ub0 = __builtin_bit_cast(int4, b0), ub1 = __builtin_bit_cast(int4, b1);
    int ua[8] = {ua0.x, ua0.y, ua0.z, ua0.w, ua1.x, ua1.y, ua1.z, ua1.w};
    int ub[8] = {ub0.x, ub0.y, ub0.z, ub0.w, ub1.x, ub1.y, ub1.z, ub1.w};
    float acc = 0.f;
    #pragma unroll
    for (int d = 0; d < 8; ++d)
        acc = __builtin_amdgcn_fdot2_f32_bf16(__builtin_bit_cast(bf16x2_t, ua[d]),
                                              __builtin_bit_cast(bf16x2_t, ub[d]),
                                              acc, false);
    return acc;
}
#else
__device__ __forceinline__ float dot16_bf16(bf16x8 a0, bf16x8 a1, bf16x8 b0, bf16x8 b1) {
    int4 ua0 = __builtin_bit_cast(int4, a0), ua1 = __builtin_bit_cast(int4, a1);
    int4 ub0 = __builtin_bit_cast(int4, b0), ub1 = __builtin_bit_cast(int4, b1);
    int ua[8] = {ua0.x, ua0.y, ua0.z, ua0.w, ua1.x, ua1.y, ua1.z, ua1.w};
    int ub[8] = {ub0.x, ub0.y, ub0.z, ub0.w, ub1.x, ub1.y, ub1.z, ub1.w};
    float acc = 0.f;
    #pragma unroll
    for (int d = 0; d < 8; ++d) {
        float alo = __builtin_bit_cast(float, ua[d] << 16);
        float ahi = __builtin_bit_cast(float, (int)(ua[d] & 0xffff0000));
        float blo = __builtin_bit_cast(float, ub[d] << 16);
        float bhi = __builtin_bit_cast(float, (int)(ub[d] & 0xffff0000));
        acc = fmaf(alo, blo, acc);
        acc = fmaf(ahi, bhi, acc);
    }
    return acc;
}
#endif

// ---------------- prep: u[k] = Wv[k,:]·wF ; c0 = bv·wF + bF ----------------
__global__ __launch_bounds__(64) void k_prep(
    const float* __restrict__ Wv, const float* __restrict__ bv,
    const float* __restrict__ wF, const float* __restrict__ bF,
    float* __restrict__ u, float* __restrict__ c0)
{
    int lane = threadIdx.x;
    float acc = 0.f;
    for (int n = 0; n < 64; ++n) acc += Wv[lane * 64 + n] * wF[n];
    u[lane] = acc;
    float p = bv[lane] * wF[lane];
    #pragma unroll
    for (int off = 32; off; off >>= 1) p += __shfl_xor(p, off, 64);
    if (lane == 0) c0[0] = p + bF[0];
}

// ---------------- k_proj: MFMA GEMM for Q, K (bf16 out) + gate ----------------
__global__ __launch_bounds__(256) void k_proj_mfma(
    const float* __restrict__ x,
    const float* __restrict__ Wq, const float* __restrict__ bq,
    const float* __restrict__ Wk, const float* __restrict__ bk,
    const float* __restrict__ u, const float* __restrict__ c0p,
    ushort_t* __restrict__ Qh, ushort_t* __restrict__ Kh,
    float* __restrict__ gate, int nNodes, int nTiles)
{
    const int tid = threadIdx.x;
    const int lane = tid & 63;
    const int w = tid >> 6;
    const int lanen = lane & 15;
    const int q = lane >> 4;

    bf16x8 Bq[2][4], Bk[2][4];
    #pragma unroll
    for (int c = 0; c < 2; ++c)
        #pragma unroll
        for (int t = 0; t < 4; ++t) {
            bf16x8 vq, vk;
            #pragma unroll
            for (int j = 0; j < 8; ++j) {
                int idx = (c * 32 + q * 8 + j) * 64 + t * 16 + lanen;
                vq[j] = (short)f2bf_fast(Wq[idx]);
                vk[j] = (short)f2bf_fast(Wk[idx]);
            }
            Bq[c][t] = vq; Bk[c][t] = vk;
        }
    float bqv[4], bkv[4];
    #pragma unroll
    for (int t = 0; t < 4; ++t) { bqv[t] = bq[t * 16 + lanen]; bkv[t] = bk[t * 16 + lanen]; }
    float ur0[8], ur1[8];
    #pragma unroll
    for (int j = 0; j < 8; ++j) { ur0[j] = u[q * 8 + j]; ur1[j] = u[32 + q * 8 + j]; }
    const float c0 = c0p[0];

    const int waveId = blockIdx.x * 4 + w;
    const int wstride = gridDim.x * 4;

    for (int tile = waveId; tile < nTiles; tile += wstride) {
        int node0 = tile * 16;
        int nodeA = node0 + lanen;
        int nodeC = (nodeA < nNodes) ? nodeA : (nNodes - 1);
        const float4* xr = (const float4*)(x + (size_t)nodeC * 64);
        float4 xa = xr[q * 2], xb = xr[q * 2 + 1];
        float4 xc = xr[8 + q * 2], xd = xr[8 + q * 2 + 1];

        float g = xa.x * ur0[0] + xa.y * ur0[1] + xa.z * ur0[2] + xa.w * ur0[3]
                + xb.x * ur0[4] + xb.y * ur0[5] + xb.z * ur0[6] + xb.w * ur0[7]
                + xc.x * ur1[0] + xc.y * ur1[1] + xc.z * ur1[2] + xc.w * ur1[3]
                + xd.x * ur1[4] + xd.y * ur1[5] + xd.z * ur1[6] + xd.w * ur1[7];
        g += __shfl_xor(g, 16);
        g += __shfl_xor(g, 32);

        bf16x8 a0, a1;
        a0[0] = (short)f2bf_fast(xa.x); a0[1] = (short)f2bf_fast(xa.y);
        a0[2] = (short)f2bf_fast(xa.z); a0[3] = (short)f2bf_fast(xa.w);
        a0[4] = (short)f2bf_fast(xb.x); a0[5] = (short)f2bf_fast(xb.y);
        a0[6] = (short)f2bf_fast(xb.z); a0[7] = (short)f2bf_fast(xb.w);
        a1[0] = (short)f2bf_fast(xc.x); a1[1] = (short)f2bf_fast(xc.y);
        a1[2] = (short)f2bf_fast(xc.z); a1[3] = (short)f2bf_fast(xc.w);
        a1[4] = (short)f2bf_fast(xd.x); a1[5] = (short)f2bf_fast(xd.y);
        a1[6] = (short)f2bf_fast(xd.z); a1[7] = (short)f2bf_fast(xd.w);

        f32x4 accq[4] = {{0,0,0,0},{0,0,0,0},{0,0,0,0},{0,0,0,0}};
        f32x4 acck[4] = {{0,0,0,0},{0,0,0,0},{0,0,0,0},{0,0,0,0}};
        #pragma unroll
        for (int t = 0; t < 4; ++t) {
            accq[t] = __builtin_amdgcn_mfma_f32_16x16x32_bf16(a0, Bq[0][t], accq[t], 0, 0, 0);
            accq[t] = __builtin_amdgcn_mfma_f32_16x16x32_bf16(a1, Bq[1][t], accq[t], 0, 0, 0);
            acck[t] = __builtin_amdgcn_mfma_f32_16x16x32_bf16(a0, Bk[0][t], acck[t], 0, 0, 0);
            acck[t] = __builtin_amdgcn_mfma_f32_16x16x32_bf16(a1, Bk[1][t], acck[t], 0, 0, 0);
        }

        #pragma unroll
        for (int t = 0; t < 4; ++t)
            #pragma unroll
            for (int r = 0; r < 4; ++r) {
                int node = node0 + q * 4 + r;
                if (node < nNodes) {
                    size_t o = (size_t)node * 64 + t * 16 + lanen;
                    Qh[o] = f2bf_fast(accq[t][r] + bqv[t]);
                    Kh[o] = f2bf_fast(acck[t][r] + bkv[t]);
                }
            }
        if (q == 0 && nodeA < nNodes) gate[nodeA] = g + c0;
    }
}

// ---------------- Pass A: edge MLP + score; emit full contribution float4 + bucket slot ----------------
__global__ __launch_bounds__(256) void k_edge_mfma(
    const int* __restrict__ ei, const int* __restrict__ ej,
    const ushort_t* __restrict__ Qh, const ushort_t* __restrict__ Kh,
    const float* __restrict__ gate, const float* __restrict__ edge_vec,
    const float* __restrict__ W1, const float* __restrict__ b1,
    const float* __restrict__ W2, const float* __restrict__ b2,
    const float* __restrict__ W3, const float* __restrict__ b3,
    unsigned* __restrict__ cnt, float4* __restrict__ evg4,
    ushort_t* __restrict__ pos16, int nEdges, long nTiles)
{
    __shared__ __align__(16) float sAttr[4][16][4];
    __shared__ __align__(16) ushort_t sH1[4][16][72];
    __shared__ __align__(16) float sBias[4][16];

    const int tid = threadIdx.x;
    const int lane = tid & 63;
    const int w = tid >> 6;
    const int lanen = lane & 15;
    const int q = lane >> 4;
    const int m2 = lane >> 2, c2 = lane & 3;

    bf16x8 Bfrag[2][4];
    #pragma unroll
    for (int c = 0; c < 2; ++c)
        #pragma unroll
        for (int t = 0; t < 4; ++t) {
            bf16x8 v;
            #pragma unroll
            for (int j = 0; j < 8; ++j)
                v[j] = (short)f2bf_fast(W2[(c * 32 + q * 8 + j) * 64 + t * 16 + lanen]);
            Bfrag[c][t] = v;
        }
    float b2r[4], w3r[4];
    #pragma unroll
    for (int t = 0; t < 4; ++t) { b2r[t] = b2[t * 16 + lanen]; w3r[t] = W3[t * 16 + lanen]; }
    const float w1x = W1[lane], w1y = W1[64 + lane], w1z = W1[128 + lane], w1w = W1[192 + lane];
    const float b1r = b1[lane];
    const float b3r = b3[0];

    const long wstride = (long)gridDim.x * 4;
    const long t0 = (long)blockIdx.x * 4 + w;

    auto idx_of = [&](long tile, int& ii, int& jj) {
        long es = tile * 16 + m2;
        long esc = (es < nEdges) ? es : (long)(nEdges - 1);
        ii = ei[esc]; jj = ej[esc];
    };
    auto gather = [&](long tile, int ii, int jj,
                      bf16x8& A, bf16x8& B, bf16x8& C, bf16x8& D, float& G, float4& AT) {
        const bf16x8* qp = (const bf16x8*)(Qh + (size_t)jj * 64);
        A = qp[c2 * 2]; B = qp[c2 * 2 + 1];
        const bf16x8* kp = (const bf16x8*)(Kh + (size_t)ii * 64);
        C = kp[c2 * 2]; D = kp[c2 * 2 + 1];
        G = gate[ii];
        if (q == 0) {
            long em = tile * 16 + lanen;
            long emc = (em < nEdges) ? em : (long)(nEdges - 1);
            float ax = edge_vec[emc * 3 + 0];
            float ay = edge_vec[emc * 3 + 1];
            float az = edge_vec[emc * 3 + 2];
            AT = make_float4(ax, ay, az, sqrtf(ax * ax + ay * ay + az * az));
        }
    };

    int iC, jC, iN, jN;
    idx_of(t0, iC, jC);
    idx_of(t0 + wstride, iN, jN);
    bf16x8 qa = {}, qb = {}, ka = {}, kb = {};
    float gte = 0.f;
    float4 attr = make_float4(0.f, 0.f, 0.f, 0.f);
    gather(t0, iC, jC, qa, qb, ka, kb, gte, attr);

    for (long tile = t0; tile < nTiles; tile += wstride) {
        wave_sync();   // WAR: prior iter's LDS reads retired
        if (q == 0) *(float4*)&sAttr[w][lanen][0] = attr;

        int iF, jF;
        idx_of(tile + 2 * wstride, iF, jF);

        wave_sync();   // sAttr visible

        #pragma unroll
        for (int m = 0; m < 16; ++m) {
            float4 a4 = *(const float4*)&sAttr[w][m][0];
            float pre = b1r + a4.x * w1x + a4.y * w1y + a4.z * w1z + a4.w * w1w;
            sH1[w][m][lane] = f2bf_fast(silu_f(pre));
        }

        float dot = dot16_bf16(qa, qb, ka, kb);
        dot += __shfl_xor(dot, 1);
        dot += __shfl_xor(dot, 2);

        wave_sync();   // sH1 visible

        bf16x8 a0 = *(const bf16x8*)&sH1[w][lanen][q * 8];
        bf16x8 a1 = *(const bf16x8*)&sH1[w][lanen][32 + q * 8];
        // fold b2 into the accumulator init (C input of MFMA)
        f32x4 acc[4];
        #pragma unroll
        for (int t = 0; t < 4; ++t)
            acc[t] = (f32x4){b2r[t], b2r[t], b2r[t], b2r[t]};
        #pragma unroll
        for (int t = 0; t < 4; ++t) {
            acc[t] = __builtin_amdgcn_mfma_f32_16x16x32_bf16(a0, Bfrag[0][t], acc[t], 0, 0, 0);
            acc[t] = __builtin_amdgcn_mfma_f32_16x16x32_bf16(a1, Bfrag[1][t], acc[t], 0, 0, 0);
        }

        float part[4] = {0.f, 0.f, 0.f, 0.f};
        #pragma unroll
        for (int t = 0; t < 4; ++t)
            #pragma unroll
            for (int r = 0; r < 4; ++r)
                part[r] += silu_f(acc[t][r]) * w3r[t];
        #pragma unroll
        for (int r = 0; r < 4; ++r) {
            part[r] += __shfl_xor(part[r], 1);
            part[r] += __shfl_xor(part[r], 2);
            part[r] += __shfl_xor(part[r], 4);
            part[r] += __shfl_xor(part[r], 8);
        }
        if (lanen == 0)
            *(float4*)&sBias[w][q * 4] = make_float4(part[0], part[1], part[2], part[3]);

        // 1-ahead gather prefetch
        bf16x8 qa2 = {}, qb2 = {}, ka2 = {}, kb2 = {};
        float gte2 = 0.f;
        float4 attr2 = make_float4(0.f, 0.f, 0.f, 0.f);
        gather(tile + wstride, iN, jN, qa2, qb2, ka2, kb2, gte2, attr2);

        wave_sync();   // sBias visible

        float bias = sBias[w][m2] + b3r;
        float ev = __expf(dot * 0.125f + bias);   // max-free softmax (scores bounded)
        long eC = tile * 16 + m2;
        if (eC < nEdges) {
            if (c2 == 0) {
                float4 a4 = *(const float4*)&sAttr[w][m2][0];
                float gg = ev * gte;
                evg4[eC] = make_float4(gg * a4.x, gg * a4.y, gg * a4.z, ev);
            } else if (c2 == 1) {
                unsigned old = atomicAdd(&cnt[jC], 1u);
                pos16[eC] = (ushort_t)old;
            }
        }

        iC = iN; jC = jN; iN = iF; jN = jF;
        qa = qa2; qb = qb2; ka = ka2; kb = kb2; gte = gte2; attr = attr2;
    }
}

// ---------------- B1: per-256-chunk exclusive scan of cnt ----------------
__global__ __launch_bounds__(256) void k_scan1(
    const unsigned* __restrict__ cnt, unsigned* __restrict__ loc,
    unsigned* __restrict__ tot, int nNodes)
{
    __shared__ unsigned s[256];
    int t = threadIdx.x;
    int j = blockIdx.x * 256 + t;
    unsigned v = (j < nNodes) ? cnt[j] : 0u;
    s[t] = v;
    __syncthreads();
    #pragma unroll
    for (int off = 1; off < 256; off <<= 1) {
        unsigned u = (t >= off) ? s[t - off] : 0u;
        __syncthreads();
        s[t] += u;
        __syncthreads();
    }
    if (j < nNodes) loc[j] = s[t] - v;   // exclusive
    if (t == 255) tot[blockIdx.x] = s[255];
}

// ---------------- B2: parallel scan of block totals (single block, LDS) ----------------
__global__ __launch_bounds__(512) void k_scan2(
    const unsigned* __restrict__ tot, unsigned* __restrict__ base, int nB)
{
    __shared__ unsigned s[512];
    int t = threadIdx.x;
    unsigned v = (t < nB) ? tot[t] : 0u;
    s[t] = v;
    __syncthreads();
    #pragma unroll
    for (int off = 1; off < 512; off <<= 1) {
        unsigned u = (t >= off) ? s[t - off] : 0u;
        __syncthreads();
        s[t] += u;
        __syncthreads();
    }
    if (t < nB) base[t] = s[t] - v;   // exclusive
}

// ---------------- C: permute contributions into sorted buckets (pure 16B copy) ----------------
__global__ __launch_bounds__(256) void k_scatter(
    const int* __restrict__ ej, const float4* __restrict__ evg4,
    const ushort_t* __restrict__ pos16, const unsigned* __restrict__ loc,
    const unsigned* __restrict__ base,
    float4* __restrict__ sorted, int nEdges)
{
    int e = blockIdx.x * 256 + threadIdx.x;
    if (e >= nEdges) return;
    int j = ej[e];
    unsigned slot = base[j >> 8] + loc[j] + (unsigned)pos16[e];
    sorted[slot] = evg4[e];
}

// ---------------- D: per-node bucket reduce + divide -> out ----------------
__global__ __launch_bounds__(256) void k_reduce(
    const unsigned* __restrict__ cnt, const unsigned* __restrict__ loc,
    const unsigned* __restrict__ base, const float4* __restrict__ sorted,
    float* __restrict__ out, int nNodes)
{
    int j = blockIdx.x * 256 + threadIdx.x;
    if (j >= nNodes) return;
    unsigned start = base[j >> 8] + loc[j];
    unsigned c = cnt[j];
    float nx = 0.f, ny = 0.f, nz = 0.f, den = 0.f;
    for (unsigned k = 0; k < c; ++k) {
        float4 v = sorted[start + k];
        nx += v.x; ny += v.y; nz += v.z; den += v.w;
    }
    float inv = 1.0f / (den + 1e-16f);
    out[(size_t)j * 3 + 0] = nx * inv;
    out[(size_t)j * 3 + 1] = ny * inv;
    out[(size_t)j * 3 + 2] = nz * inv;
}

extern "C" void kernel_launch(void* const* d_in, const int* in_sizes, int n_in,
                              void* d_out, int out_size, void* d_ws, size_t ws_size,
                              hipStream_t stream)
{
    const float* x        = (const float*)d_in[0];
    const float* edge_vec = (const float*)d_in[1];
    const float* Wq = (const float*)d_in[2];
    const float* bq = (const float*)d_in[3];
    const float* Wk = (const float*)d_in[4];
    const float* bk = (const float*)d_in[5];
    const float* Wv = (const float*)d_in[6];
    const float* bv = (const float*)d_in[7];
    const float* W1 = (const float*)d_in[8];
    const float* b1 = (const float*)d_in[9];
    const float* W2 = (const float*)d_in[10];
    const float* b2 = (const float*)d_in[11];
    const float* W3 = (const float*)d_in[12];
    const float* b3 = (const float*)d_in[13];
    const float* wF = (const float*)d_in[14];
    const float* bF = (const float*)d_in[15];
    const int*   eidx = (const int*)d_in[16];

    int nNodes = in_sizes[0] / DIM;
    int nEdges = in_sizes[16] / 2;
    const int* ei = eidx;
    const int* ej = eidx + nEdges;
    int nB = (nNodes + 255) / 256;   // 391 <= 512

    // ws layout: [region0: Qh+Kh (life: proj..A) ALIASED with sorted (life: C..D)]
    char* p = (char*)d_ws;
    ushort_t* Qh = (ushort_t*)p;
    ushort_t* Kh = Qh + (size_t)nNodes * DIM;
    float4* sorted = (float4*)p;                       // aliases Qh/Kh (dead after pass A)
    p += (size_t)nNodes * DIM * 2 * sizeof(ushort_t);
    float* gate = (float*)p;          p += (size_t)nNodes * sizeof(float);
    unsigned* cnt = (unsigned*)p;     p += (size_t)nNodes * sizeof(unsigned);
    unsigned* loc = (unsigned*)p;     p += (size_t)nNodes * sizeof(unsigned);
    unsigned* base = (unsigned*)p;    p += (size_t)((nB + 63) & ~63) * sizeof(unsigned);
    unsigned* tot = (unsigned*)p;     p += (size_t)((nB + 63) & ~63) * sizeof(unsigned);
    float* u = (float*)p;             p += 64 * sizeof(float);
    float* c0 = (float*)p;            p += 64 * sizeof(float);
    float4* evg4 = (float4*)p;        p += (size_t)nEdges * sizeof(float4);
    ushort_t* pos16 = (ushort_t*)p;   p += (size_t)nEdges * sizeof(ushort_t);

    float* out = (float*)d_out;
    hipMemsetAsync(cnt, 0, (size_t)nNodes * sizeof(unsigned), stream);

    k_prep<<<1, 64, 0, stream>>>(Wv, bv, wF, bF, u, c0);

    int nTilesN = (nNodes + 15) / 16;
    k_proj_mfma<<<256, 256, 0, stream>>>(x, Wq, bq, Wk, bk, u, c0,
                                         Qh, Kh, gate, nNodes, nTilesN);

    long nTilesE = (nEdges + 15) / 16;
    k_edge_mfma<<<1792, 256, 0, stream>>>(ei, ej, Qh, Kh, gate, edge_vec,
                                          W1, b1, W2, b2, W3, b3,
                                          cnt, evg4, pos16, nEdges, nTilesE);

    k_scan1<<<nB, 256, 0, stream>>>(cnt, loc, tot, nNodes);
    k_scan2<<<1, 512, 0, stream>>>(tot, base, nB);

    int nbE = (nEdges + 255) / 256;
    k_scatter<<<nbE, 256, 0, stream>>>(ej, evg4, pos16, loc, base, sorted, nEdges);

    k_reduce<<<nB, 256, 0, stream>>>(cnt, loc, base, sorted, out, nNodes);
}